// Round 1
// 668.187 us; speedup vs baseline: 1.1291x; 1.1291x over previous
//
#include <hip/hip_runtime.h>
#include <stdint.h>

typedef unsigned short ushort_t;
typedef __attribute__((ext_vector_type(8))) short bf16x8;
typedef __attribute__((ext_vector_type(4))) float f32x4;

#define BB 2
#define SS 2048
#define DD 1024
#define HH 16
#define HDD 64
#define MEMM 512
#define KTOT 2560   // MEMM + SS
#define NROWS (BB*HH*SS)   // 65536 score rows

// ---------- helpers ----------
__device__ __forceinline__ float bf2f(uint32_t u) {
    return __uint_as_float(u << 16);
}
__device__ __forceinline__ ushort_t f2bf(float f) {
    uint32_t u = __float_as_uint(f);
    uint32_t r = (u + 0x7FFFu + ((u >> 16) & 1u)) >> 16;
    return (ushort_t)r;
}
__device__ __forceinline__ uint32_t mapkey(uint32_t u) {
    return (u & 0x8000u) ? (0xFFFFu ^ u) : (u | 0x8000u);
}
__device__ __forceinline__ uint32_t unmapkey(uint32_t k) {
    return (k & 0x8000u) ? (k ^ 0x8000u) : (0xFFFFu ^ k);
}

// ---------- cast hidden f32 -> bf16 ----------
__global__ __launch_bounds__(256) void cast_hidden_kernel(
    const float* __restrict__ h, ushort_t* __restrict__ hb)
{
    size_t i0 = ((size_t)blockIdx.x * 256 + threadIdx.x) * 16;  // 4M elems / 16
    ushort_t o[16];
#pragma unroll
    for (int j = 0; j < 4; ++j) {
        float4 v = *(const float4*)&h[i0 + j * 4];
        o[j * 4 + 0] = f2bf(v.x); o[j * 4 + 1] = f2bf(v.y);
        o[j * 4 + 2] = f2bf(v.z); o[j * 4 + 3] = f2bf(v.w);
    }
    *(uint4*)&hb[i0] = *(uint4*)&o[0];
    *(uint4*)&hb[i0 + 8] = *(uint4*)&o[8];
}

// ---------- transpose+cast weights: W[k][n] f32 -> Wt[n][k] bf16 ----------
__global__ __launch_bounds__(256) void transw_kernel(
    const float* __restrict__ Wq, const float* __restrict__ Wk,
    const float* __restrict__ Wv, const float* __restrict__ Wo,
    ushort_t* __restrict__ WtAll)
{
    __shared__ ushort_t T[64][66];
    const int z = blockIdx.z;
    const float* W = (z == 0) ? Wq : (z == 1) ? Wk : (z == 2) ? Wv : Wo;
    ushort_t* dst = WtAll + (size_t)z * DD * DD;
    const int k0 = blockIdx.x * 64, n0 = blockIdx.y * 64;
    const int t = threadIdx.x;
    const int kk = t >> 2, c4 = (t & 3) * 16;
#pragma unroll
    for (int j = 0; j < 4; ++j) {
        float4 v = *(const float4*)&W[(size_t)(k0 + kk) * DD + n0 + c4 + j * 4];
        T[kk][c4 + j * 4 + 0] = f2bf(v.x);
        T[kk][c4 + j * 4 + 1] = f2bf(v.y);
        T[kk][c4 + j * 4 + 2] = f2bf(v.z);
        T[kk][c4 + j * 4 + 3] = f2bf(v.w);
    }
    __syncthreads();
    const int nn = t >> 2, kc = (t & 3) * 16;
    ushort_t tmp[16];
#pragma unroll
    for (int j = 0; j < 16; ++j) tmp[j] = T[kc + j][nn];
    *(uint4*)&dst[(size_t)(n0 + nn) * DD + k0 + kc] = *(uint4*)&tmp[0];
    *(uint4*)&dst[(size_t)(n0 + nn) * DD + k0 + kc + 8] = *(uint4*)&tmp[8];
}

// ---------- 128x128-tile bf16 MFMA GEMM (m93-style LDS staging) ----------
__global__ __launch_bounds__(256) void gemm128_kernel(
    const ushort_t* __restrict__ A, const ushort_t* __restrict__ Bt, int mode,
    const float* __restrict__ bq, const float* __restrict__ bk, const float* __restrict__ bv,
    float* __restrict__ outf,
    ushort_t* __restrict__ q_bf, ushort_t* __restrict__ kbf, ushort_t* __restrict__ vbf,
    float* __restrict__ nk, float* __restrict__ nv)
{
    __shared__ __align__(16) ushort_t As[128 * 32];
    __shared__ __align__(16) ushort_t Bs[128 * 32];
    const int tid = threadIdx.x;
    const int lane = tid & 63, w = tid >> 6;
    const int wm = w >> 1, wn = w & 1;
    const int row16 = lane & 15, quad = lane >> 4;
    const int n0 = blockIdx.x * 128, m0 = blockIdx.y * 128;

    const int r0 = tid >> 2, c0 = (tid & 3) * 8;
    const int r1 = (tid + 256) >> 2, c1 = ((tid + 256) & 3) * 8;

    f32x4 acc[4][4];
#pragma unroll
    for (int i = 0; i < 4; ++i)
#pragma unroll
        for (int j = 0; j < 4; ++j) acc[i][j] = (f32x4){0.f, 0.f, 0.f, 0.f};

    for (int k0 = 0; k0 < DD; k0 += 32) {
        *(uint4*)&As[tid * 8]         = *(const uint4*)&A [(size_t)(m0 + r0) * DD + k0 + c0];
        *(uint4*)&As[(tid + 256) * 8] = *(const uint4*)&A [(size_t)(m0 + r1) * DD + k0 + c1];
        *(uint4*)&Bs[tid * 8]         = *(const uint4*)&Bt[(size_t)(n0 + r0) * DD + k0 + c0];
        *(uint4*)&Bs[(tid + 256) * 8] = *(const uint4*)&Bt[(size_t)(n0 + r1) * DD + k0 + c1];
        __syncthreads();
        bf16x8 af[4], bfr[4];
#pragma unroll
        for (int mt = 0; mt < 4; ++mt)
            af[mt] = *(const bf16x8*)&As[(wm * 64 + mt * 16 + row16) * 32 + quad * 8];
#pragma unroll
        for (int nt = 0; nt < 4; ++nt)
            bfr[nt] = *(const bf16x8*)&Bs[(wn * 64 + nt * 16 + row16) * 32 + quad * 8];
#pragma unroll
        for (int mt = 0; mt < 4; ++mt)
#pragma unroll
            for (int nt = 0; nt < 4; ++nt)
                acc[mt][nt] = __builtin_amdgcn_mfma_f32_16x16x32_bf16(
                    af[mt], bfr[nt], acc[mt][nt], 0, 0, 0);
        __syncthreads();
    }

#pragma unroll
    for (int nt = 0; nt < 4; ++nt) {
        const int nb = n0 + wn * 64 + nt * 16;       // tile-uniform
        if (mode == 0) {
#pragma unroll
            for (int mt = 0; mt < 4; ++mt) {
#pragma unroll
                for (int r = 0; r < 4; ++r) {
                    int m = m0 + wm * 64 + mt * 16 + quad * 4 + r;
                    int n = nb + row16;
                    outf[(size_t)m * DD + n] = acc[mt][nt][r] + bq[n];
                }
            }
        } else {
            const int sel = nb >> 10;
            const float* bias = (sel == 0) ? bq : (sel == 1) ? bk : bv;
#pragma unroll
            for (int mt = 0; mt < 4; ++mt) {
#pragma unroll
                for (int r = 0; r < 4; ++r) {
                    int m = m0 + wm * 64 + mt * 16 + quad * 4 + r;
                    int nn = (nb + row16) & 1023;
                    float v = acc[mt][nt][r] + bias[nn];
                    int b = m >> 11, s = m & (SS - 1);
                    int h = nn >> 6, d = nn & 63;
                    size_t bh = (size_t)b * HH + h;
                    if (sel == 0) {
                        q_bf[(bh * SS + s) * HDD + d] = f2bf(v);
                    } else {
                        ushort_t* dst = (sel == 1) ? kbf : vbf;
                        dst[(bh * KTOT + MEMM + s) * HDD + d] = f2bf(v);
                        if (s >= SS - MEMM) {
                            float* nf = (sel == 1) ? nk : nv;
                            nf[(bh * MEMM + (s - (SS - MEMM))) * HDD + d] = v;
                        }
                    }
                }
            }
        }
    }
}

// ---------- cast past_k/past_v f32 -> bf16 cache heads ----------
__global__ __launch_bounds__(256) void cast_past_kernel(
    const float* __restrict__ pk, const float* __restrict__ pv,
    ushort_t* __restrict__ kbf, ushort_t* __restrict__ vbf)
{
    int idx = blockIdx.x * 256 + threadIdx.x;  // BB*HH*MEMM*HDD = 1048576
    int bh = idx >> 15;
    int rem = idx & 32767;
    size_t dst = (size_t)bh * KTOT * HDD + rem;
    kbf[dst] = f2bf(pk[idx]);
    vbf[dst] = f2bf(pv[idx]);
}

// ---------- transpose V: vbf[bh][k][d] -> vt[bh][d][k] ----------
__global__ __launch_bounds__(256) void transpose_v_kernel(
    const ushort_t* __restrict__ vbf, ushort_t* __restrict__ vt)
{
    __shared__ ushort_t T[64][72];
    const int k0 = blockIdx.x * 64;
    const int bh = blockIdx.y;
    const int t = threadIdx.x;
    const int rr = t >> 3, cc = (t & 7) * 8;
#pragma unroll
    for (int p = 0; p < 2; ++p) {
        int kk = p * 32 + rr;
        *(uint4*)&T[kk][cc] =
            *(const uint4*)(vbf + ((size_t)bh * KTOT + k0 + kk) * HDD + cc);
    }
    __syncthreads();
#pragma unroll
    for (int p = 0; p < 2; ++p) {
        int d = p * 32 + rr;
        ushort_t tmp[8];
#pragma unroll
        for (int j = 0; j < 8; ++j) tmp[j] = T[cc + j][d];
        *(uint4*)(vt + ((size_t)bh * HDD + d) * KTOT + k0 + cc) = *(uint4*)tmp;
    }
}

// ---------- scores: MFMA (K prefetch), wave-private LDS transpose, ----------
// ---------- fully-contiguous stores, no barriers ----------
__global__ __launch_bounds__(256) void score_kernel(
    const ushort_t* __restrict__ qbf, const ushort_t* __restrict__ kbf,
    ushort_t* __restrict__ sbuf, int bh0)
{
    __shared__ __align__(16) ushort_t Ts[64][264];
    const int w = threadIdx.x >> 6, lane = threadIdx.x & 63;
    const int kt = blockIdx.x, qt = blockIdx.y;
    const int lbh = blockIdx.z, bh = bh0 + lbh;
    const int m0 = qt * 64 + w * 16;
    const int row16 = lane & 15, quad = lane >> 4;

    const ushort_t* qrow = qbf + ((size_t)bh * SS + m0 + row16) * HDD + quad * 8;
    bf16x8 a0 = *(const bf16x8*)qrow;
    bf16x8 a1 = *(const bf16x8*)(qrow + 32);
    const ushort_t* kbase = kbf + ((size_t)bh * KTOT + kt * 256 + row16) * HDD + quad * 8;

    bf16x8 b0c = *(const bf16x8*)kbase;
    bf16x8 b1c = *(const bf16x8*)(kbase + 32);
#pragma unroll
    for (int nt = 0; nt < 16; ++nt) {
        bf16x8 b0n, b1n;
        if (nt < 15) {
            const ushort_t* kr = kbase + (size_t)(nt + 1) * 16 * HDD;
            b0n = *(const bf16x8*)kr;
            b1n = *(const bf16x8*)(kr + 32);
        }
        f32x4 acc = {0.f, 0.f, 0.f, 0.f};
        acc = __builtin_amdgcn_mfma_f32_16x16x32_bf16(a0, b0c, acc, 0, 0, 0);
        acc = __builtin_amdgcn_mfma_f32_16x16x32_bf16(a1, b1c, acc, 0, 0, 0);
#pragma unroll
        for (int r = 0; r < 4; ++r)
            Ts[w * 16 + quad * 4 + r][nt * 16 + row16] = f2bf(acc[r] * 0.125f);
        b0c = b0n; b1c = b1n;
    }
    // wave-private transpose readback: wave w only touches rows w*16..w*16+15,
    // which it alone wrote -> no __syncthreads needed (in-wave lgkmcnt ordering).
    const int cc = (lane & 31) * 8, rsel = lane >> 5;
    ushort_t* dstb = sbuf + ((size_t)lbh * SS + qt * 64) * KTOT + kt * 256;
#pragma unroll
    for (int j = 0; j < 8; ++j) {
        int r = w * 16 + j * 2 + rsel;
        *(uint4*)&dstb[(size_t)r * KTOT + cc] = *(const uint4*)&Ts[r][cc];
    }
}

// ---------- wave helpers ----------
__device__ __forceinline__ uint32_t wave_iscan(uint32_t x, int lane) {
#pragma unroll
    for (int d = 1; d < 64; d <<= 1) {
        uint32_t t = __shfl_up(x, d, 64);
        if (lane >= d) x += t;
    }
    return x;
}
__device__ __forceinline__ void select_from_counts(
    const uint32_t* c, uint32_t R, int lane, uint32_t* bin_out, uint32_t* rem_out)
{
    uint32_t s = c[0] + c[1] + c[2] + c[3];
    uint32_t incl = wave_iscan(s, lane);
    uint32_t excl = incl - s;
    uint64_t bal = __ballot(incl > R);
    int fl = __ffsll((unsigned long long)bal) - 1;
    uint32_t exf = __shfl(excl, fl, 64);
    uint32_t c0 = __shfl(c[0], fl, 64), c1 = __shfl(c[1], fl, 64);
    uint32_t c2 = __shfl(c[2], fl, 64), c3 = __shfl(c[3], fl, 64);
    uint32_t cc[4] = {c0, c1, c2, c3};
    uint32_t cum = exf, bin = fl * 4, rem = 0;
#pragma unroll
    for (int i = 0; i < 4; ++i) {
        if (cum + cc[i] > R) { bin = fl * 4 + i; rem = R - cum; break; }
        cum += cc[i];
    }
    *bin_out = bin;
    *rem_out = rem;
}

__device__ __forceinline__ void clear_hist(uint32_t* H, int lane) {
    const uint4 z4 = {0u, 0u, 0u, 0u};
#pragma unroll
    for (int i = 0; i < 4; ++i) *(uint4*)&H[lane * 4 + i * 256] = z4;
    if (lane < 4) *(uint4*)&H[1024 + lane * 4] = z4;
}

// generic exact rank-R select over the wave's 40x64 raw bf16 keys (mapped-key
// two-level histogram; correctness fallback, ~never executed). Returns raw bf16.
__device__ __forceinline__ uint32_t slow_rank_key(
    const uint4* W, uint32_t R, uint32_t* H, int rep, int lane)
{
    clear_hist(H, lane);
    __threadfence_block();
#pragma unroll
    for (int c = 0; c < 5; ++c) {
        uint32_t ww[4] = {W[c].x, W[c].y, W[c].z, W[c].w};
#pragma unroll
        for (int q = 0; q < 4; ++q) {
            uint32_t m0 = mapkey(ww[q] & 0xFFFFu);
            uint32_t m1 = mapkey(ww[q] >> 16);
            atomicAdd(&H[rep * 260 + (m0 >> 8)], 1u);
            atomicAdd(&H[rep * 260 + (m1 >> 8)], 1u);
        }
    }
    __threadfence_block();
    uint32_t c4[4];
#pragma unroll
    for (int i = 0; i < 4; ++i)
        c4[i] = H[lane * 4 + i] + H[260 + lane * 4 + i]
              + H[520 + lane * 4 + i] + H[780 + lane * 4 + i];
    uint32_t binM, rem;
    select_from_counts(c4, R, lane, &binM, &rem);
    clear_hist(H, lane);
    __threadfence_block();
#pragma unroll
    for (int c = 0; c < 5; ++c) {
        uint32_t ww[4] = {W[c].x, W[c].y, W[c].z, W[c].w};
#pragma unroll
        for (int q = 0; q < 4; ++q) {
            uint32_t m0 = mapkey(ww[q] & 0xFFFFu);
            uint32_t m1 = mapkey(ww[q] >> 16);
            if ((m0 >> 8) == binM) atomicAdd(&H[rep * 260 + (m0 & 255u)], 1u);
            if ((m1 >> 8) == binM) atomicAdd(&H[rep * 260 + (m1 & 255u)], 1u);
        }
    }
    __threadfence_block();
#pragma unroll
    for (int i = 0; i < 4; ++i)
        c4[i] = H[lane * 4 + i] + H[260 + lane * 4 + i]
              + H[520 + lane * 4 + i] + H[780 + lane * 4 + i];
    uint32_t low, r2;
    select_from_counts(c4, rem, lane, &low, &r2);
    return unmapkey((binM << 8) | low);
}

// ---------- per-row quantile (ranks 255,256), 1 wave per row ----------
// Fast path: raw-bf16 top-byte bins. For the bottom-10% rank of a score row the
// threshold lands in t=0xC0 (-8,-2], 0xBF (-2,-0.5] or 0xBE (-0.5,-0.125].
// Pass 1 (registers only, 9 VALU/key): count t>=0xC1 and the 3 candidate bins;
// cumulative counts give the exact bin+rank. Pass 2: one 256-entry LDS
// histogram of in-bin low bytes (^0xFF: negative bins are value-descending in
// the mantissa) -> exact key. Generic slow path kept for all other cases.
__global__ __launch_bounds__(256) void quant_kernel(
    const ushort_t* __restrict__ sbuf, float* __restrict__ thr_out, int bh0)
{
    __shared__ __align__(16) uint32_t hist[4][1040];   // [wave][replica*260 + bin]
    const int w = threadIdx.x >> 6, lane = threadIdx.x & 63;
    const int rep = lane >> 4;
    uint32_t* H = hist[w];
    const int lrow = blockIdx.x * 4 + w;
    const size_t grow = (size_t)bh0 * SS + lrow;
    const ushort_t* src = sbuf + (size_t)lrow * KTOT;

    uint4 W[5];
#pragma unroll
    for (int c = 0; c < 5; ++c) W[c] = *(const uint4*)(src + c * 512 + lane * 8);

    // pass 1: 4 register counters over raw top bytes
    uint32_t nBel = 0, nA = 0, nB = 0, nC = 0;
#pragma unroll
    for (int c = 0; c < 5; ++c) {
        uint32_t ww[4] = {W[c].x, W[c].y, W[c].z, W[c].w};
#pragma unroll
        for (int q = 0; q < 4; ++q) {
            uint32_t t0 = (ww[q] >> 8) & 255u, t1 = ww[q] >> 24;
            nBel += (t0 >= 0xC1u); nBel += (t1 >= 0xC1u);
            nA   += (t0 == 0xC0u); nA   += (t1 == 0xC0u);
            nB   += (t0 == 0xBFu); nB   += (t1 == 0xBFu);
            nC   += (t0 == 0xBEu); nC   += (t1 == 0xBEu);
        }
    }
    uint32_t p0 = nBel | (nA << 16), p1 = nB | (nC << 16);
#pragma unroll
    for (int d = 1; d < 64; d <<= 1) {
        p0 += (uint32_t)__shfl_xor(p0, d, 64);
        p1 += (uint32_t)__shfl_xor(p1, d, 64);
    }
    const uint32_t C0 = p0 & 0xFFFFu;
    const uint32_t C1 = C0 + (p0 >> 16);
    const uint32_t C2 = C1 + (p1 & 0xFFFFu);
    const uint32_t C3 = C2 + (p1 >> 16);

    uint32_t tbA = 0, remA = 0, tbB = 0, remB = 0;
    bool okA = true, okB = true;
    if (255u < C0)      okA = false;
    else if (255u < C1) { tbA = 0xC0u; remA = 255u - C0; }
    else if (255u < C2) { tbA = 0xBFu; remA = 255u - C1; }
    else if (255u < C3) { tbA = 0xBEu; remA = 255u - C2; }
    else okA = false;
    if (256u < C0)      okB = false;
    else if (256u < C1) { tbB = 0xC0u; remB = 256u - C0; }
    else if (256u < C2) { tbB = 0xBFu; remB = 256u - C1; }
    else if (256u < C3) { tbB = 0xBEu; remB = 256u - C2; }
    else okB = false;

    uint32_t rawA, rawB;
    if (okA && okB) {
        clear_hist(H, lane);
        __threadfence_block();
#pragma unroll
        for (int c = 0; c < 5; ++c) {
            uint32_t ww[4] = {W[c].x, W[c].y, W[c].z, W[c].w};
#pragma unroll
            for (int q = 0; q < 4; ++q) {
                uint32_t t0 = (ww[q] >> 8) & 255u, t1 = ww[q] >> 24;
                if (t0 == tbA) atomicAdd(&H[rep * 260 + ((ww[q] & 255u) ^ 255u)], 1u);
                if (t1 == tbA) atomicAdd(&H[rep * 260 + (((ww[q] >> 16) & 255u) ^ 255u)], 1u);
            }
        }
        __threadfence_block();
        uint32_t c4[4];
#pragma unroll
        for (int i = 0; i < 4; ++i)
            c4[i] = H[lane * 4 + i] + H[260 + lane * 4 + i]
                  + H[520 + lane * 4 + i] + H[780 + lane * 4 + i];
        uint32_t idxA, rr;
        select_from_counts(c4, remA, lane, &idxA, &rr);
        rawA = (tbA << 8) | (idxA ^ 255u);
        if (tbB == tbA) {
            uint32_t idxB;
            select_from_counts(c4, remB, lane, &idxB, &rr);
            rawB = (tbA << 8) | (idxB ^ 255u);
        } else {
            clear_hist(H, lane);
            __threadfence_block();
#pragma unroll
            for (int c = 0; c < 5; ++c) {
                uint32_t ww[4] = {W[c].x, W[c].y, W[c].z, W[c].w};
#pragma unroll
                for (int q = 0; q < 4; ++q) {
                    uint32_t t0 = (ww[q] >> 8) & 255u, t1 = ww[q] >> 24;
                    if (t0 == tbB) atomicAdd(&H[rep * 260 + ((ww[q] & 255u) ^ 255u)], 1u);
                    if (t1 == tbB) atomicAdd(&H[rep * 260 + (((ww[q] >> 16) & 255u) ^ 255u)], 1u);
                }
            }
            __threadfence_block();
#pragma unroll
            for (int i = 0; i < 4; ++i)
                c4[i] = H[lane * 4 + i] + H[260 + lane * 4 + i]
                      + H[520 + lane * 4 + i] + H[780 + lane * 4 + i];
            uint32_t idxB;
            select_from_counts(c4, remB, lane, &idxB, &rr);
            rawB = (tbB << 8) | (idxB ^ 255u);
        }
    } else {
        rawA = slow_rank_key(W, 255u, H, rep, lane);
        rawB = slow_rank_key(W, 256u, H, rep, lane);
    }

    if (lane == 0) {
        float fA = bf2f(rawA);
        float fB = bf2f(rawB);
        thr_out[grow] = fA + 0.9f * (fB - fA);
    }
}

// ---------- softmax + PV, barrier-free: wave = 16-row stripe, no LDS ----------
// No running-max subtraction: out = exp(s)*V / sum(exp(s)) is exact after
// normalization; |s| <~ 6 for this problem (f32 exp safe to ~88), bf16
// relative rounding of the weights is scale-invariant.
__global__ __launch_bounds__(256) void pv_kernel(
    const ushort_t* __restrict__ sbuf, const ushort_t* __restrict__ vt,
    const float* __restrict__ thr_arr,
    const int* __restrict__ amask, ushort_t* __restrict__ attn_bf, int bh0)
{
    const int tid = threadIdx.x;
    const int lane = tid & 63, w = tid >> 6;
    const int row16 = lane & 15, quad = lane >> 4;
    const int qt = blockIdx.x;
    const int lbh = blockIdx.y, bh = bh0 + lbh;
    const int b = bh >> 4, h = bh & 15;
    const int m0 = qt * 64 + w * 16;     // this wave's first row

    const ushort_t* arow = sbuf + ((size_t)lbh * SS + m0 + row16) * KTOT + quad * 8;
    const ushort_t* brow = vt + ((size_t)bh * HDD + row16) * KTOT + quad * 8;
    const float thr = thr_arr[(size_t)bh * SS + m0 + row16];
    const int* amq = amask + b * SS + quad * 8;   // + (k0 - MEMM) per step

    f32x4 acc[4];
#pragma unroll
    for (int i = 0; i < 4; ++i) acc[i] = (f32x4){0.f, 0.f, 0.f, 0.f};
    float psum = 0.f;

    uint4 a_nxt = *(const uint4*)arow;
    uint4 b_nxt[4];
#pragma unroll
    for (int nt = 0; nt < 4; ++nt)
        b_nxt[nt] = *(const uint4*)(brow + (size_t)nt * 16 * KTOT);
    int4 m_nxt0 = {1, 1, 1, 1}, m_nxt1 = {1, 1, 1, 1};

    for (int k0 = 0; k0 < KTOT; k0 += 32) {
        uint4 a_cur = a_nxt;
        uint4 b_cur[4] = {b_nxt[0], b_nxt[1], b_nxt[2], b_nxt[3]};
        int4 mc0 = m_nxt0, mc1 = m_nxt1;
        const int kn = k0 + 32;
        if (kn < KTOT) {
            a_nxt = *(const uint4*)(arow + kn);
#pragma unroll
            for (int nt = 0; nt < 4; ++nt)
                b_nxt[nt] = *(const uint4*)(brow + (size_t)nt * 16 * KTOT + kn);
            if (kn >= MEMM) {
                m_nxt0 = *(const int4*)(amq + kn - MEMM);
                m_nxt1 = *(const int4*)(amq + kn - MEMM + 4);
            }
        }
        uint32_t u[8] = {a_cur.x & 0xFFFFu, a_cur.x >> 16, a_cur.y & 0xFFFFu, a_cur.y >> 16,
                         a_cur.z & 0xFFFFu, a_cur.z >> 16, a_cur.w & 0xFFFFu, a_cur.w >> 16};
        int mm[8] = {mc0.x, mc0.y, mc0.z, mc0.w, mc1.x, mc1.y, mc1.z, mc1.w};
        const bool masked = (k0 >= MEMM);
        ushort_t wb[8];
        float ps = 0.f;
#pragma unroll
        for (int j = 0; j < 8; ++j) {
            float s = bf2f(u[j]);
            bool keep = (s >= thr);
            if (masked) keep = keep && (mm[j] != 0);
            float wv = keep ? __expf(s) : 0.f;
            ushort_t q = f2bf(wv);
            wb[j] = q;
            ps += bf2f((uint32_t)q);
        }
        psum += ps;
        uint4 aq;
        aq.x = (uint32_t)wb[0] | ((uint32_t)wb[1] << 16);
        aq.y = (uint32_t)wb[2] | ((uint32_t)wb[3] << 16);
        aq.z = (uint32_t)wb[4] | ((uint32_t)wb[5] << 16);
        aq.w = (uint32_t)wb[6] | ((uint32_t)wb[7] << 16);
        bf16x8 af;
        *(uint4*)&af = aq;
#pragma unroll
        for (int nt = 0; nt < 4; ++nt) {
            bf16x8 bf;
            *(uint4*)&bf = b_cur[nt];
            acc[nt] = __builtin_amdgcn_mfma_f32_16x16x32_bf16(af, bf, acc[nt], 0, 0, 0);
        }
    }

    psum += __shfl_xor(psum, 16, 64);
    psum += __shfl_xor(psum, 32, 64);

#pragma unroll
    for (int nt = 0; nt < 4; ++nt) {
#pragma unroll
        for (int r = 0; r < 4; ++r) {
            int row = quad * 4 + r;
            float rs = __shfl(psum, row, 64);
            float val = acc[nt][r] / rs;
            attn_bf[((size_t)b * SS + m0 + row) * DD + h * HDD + nt * 16 + row16] = f2bf(val);
        }
    }
}

extern "C" void kernel_launch(void* const* d_in, const int* in_sizes, int n_in,
                              void* d_out, int out_size, void* d_ws, size_t ws_size,
                              hipStream_t stream)
{
    const float* hidden = (const float*)d_in[0];
    const int*   amask  = (const int*)d_in[1];
    const float* past_k = (const float*)d_in[2];
    const float* past_v = (const float*)d_in[3];
    const float* Wq = (const float*)d_in[4];
    const float* bq = (const float*)d_in[5];
    const float* Wk = (const float*)d_in[6];
    const float* bk = (const float*)d_in[7];
    const float* Wv = (const float*)d_in[8];
    const float* bv = (const float*)d_in[9];
    const float* Wo = (const float*)d_in[10];
    const float* bo = (const float*)d_in[11];

    float* out    = (float*)d_out;
    float* nk_out = out + (size_t)BB * SS * DD;
    float* nv_out = nk_out + (size_t)BB * HH * MEMM * HDD;

    char* base = (char*)d_ws;
    size_t off = 0;
    auto alloc = [&](size_t bytes) {
        char* p = base + off;
        off += (bytes + 255) & ~(size_t)255;
        return p;
    };
    ushort_t* hb    = (ushort_t*)alloc((size_t)BB * SS * DD * 2);            // 8 MB
    ushort_t* WtAll = (ushort_t*)alloc((size_t)4 * DD * DD * 2);             // 8 MB
    ushort_t* q_bf  = (ushort_t*)alloc((size_t)BB * HH * SS * HDD * 2);      // 8 MB
    ushort_t* kbf   = (ushort_t*)alloc((size_t)BB * HH * KTOT * HDD * 2);    // 10 MB
    ushort_t* vbf   = (ushort_t*)alloc((size_t)BB * HH * KTOT * HDD * 2);    // 10 MB
    ushort_t* vt    = (ushort_t*)alloc((size_t)BB * HH * HDD * KTOT * 2);    // 10 MB
    ushort_t* abf   = (ushort_t*)alloc((size_t)BB * SS * DD * 2);            // 8 MB
    float* thr_arr  = (float*)alloc((size_t)NROWS * 4);
    size_t fixed = off;
    const size_t sbuf_full = (size_t)BB * HH * SS * KTOT * 2;                // 335.5 MB
    int nchunks = 32;
    for (int c = 1; c <= 32; c <<= 1) {
        if (fixed + sbuf_full / c + 256 <= ws_size) { nchunks = c; break; }
    }
    ushort_t* sbuf = (ushort_t*)alloc(sbuf_full / nchunks);
    const int bhpc = (BB * HH) / nchunks;

    dim3 blk(256);

    cast_hidden_kernel<<<dim3(1024), blk, 0, stream>>>(hidden, hb);
    transw_kernel<<<dim3(16, 16, 4), blk, 0, stream>>>(Wq, Wk, Wv, Wo, WtAll);
    // fused QKV: one GEMM, N=3072 (Wq|Wk|Wv transposes adjacent in WtAll)
    gemm128_kernel<<<dim3(24, 32), blk, 0, stream>>>(
        hb, WtAll, 1, bq, bk, bv, nullptr, q_bf, kbf, vbf, nk_out, nv_out);
    cast_past_kernel<<<dim3(4096), blk, 0, stream>>>(past_k, past_v, kbf, vbf);
    transpose_v_kernel<<<dim3(KTOT / 64, BB * HH), blk, 0, stream>>>(vbf, vt);

    for (int ci = 0; ci < nchunks; ++ci) {
        int bh0 = ci * bhpc;
        score_kernel<<<dim3(KTOT / 256, SS / 64, bhpc), blk, 0, stream>>>(q_bf, kbf, sbuf, bh0);
        quant_kernel<<<dim3(bhpc * (SS / 4)), blk, 0, stream>>>(sbuf, thr_arr, bh0);
        pv_kernel<<<dim3(SS / 64, bhpc), blk, 0, stream>>>(sbuf, vt, thr_arr,
                                                           amask, abf, bh0);
    }
    // O-projection
    gemm128_kernel<<<dim3(8, 32), blk, 0, stream>>>(
        abf, WtAll + (size_t)3 * DD * DD, 0, bo, nullptr, nullptr, out,
        nullptr, nullptr, nullptr, nullptr, nullptr);
}